// Round 8
// baseline (267.120 us; speedup 1.0000x reference)
//
#include <hip/hip_runtime.h>
#include <cmath>

#define EPS_BN 1e-5f

typedef __bf16 bf16;
typedef __bf16 bf16x4 __attribute__((ext_vector_type(4)));
typedef __bf16 bf16x8 __attribute__((ext_vector_type(8)));
typedef float  f32x4  __attribute__((ext_vector_type(4)));

// ---------------------------------------------------------------------------
// Kernel 1: all preprocessing elementwise work in one launch. (unchanged R7)
// ---------------------------------------------------------------------------
__global__ __launch_bounds__(256) void conv_all_kernel(
    const float* __restrict__ x,
    const float* __restrict__ qdw, const float* __restrict__ qscale,
    const float* __restrict__ qbias, const float* __restrict__ qmean,
    const float* __restrict__ qvar,
    const float* __restrict__ kdw, const float* __restrict__ kscale,
    const float* __restrict__ kbias, const float* __restrict__ kmean,
    const float* __restrict__ kvar,
    const float* __restrict__ vdw, const float* __restrict__ vscale,
    const float* __restrict__ vbias, const float* __restrict__ vmean,
    const float* __restrict__ vvar,
    const float* __restrict__ qpw, const float* __restrict__ kpw,
    const float* __restrict__ vpw,
    bf16* __restrict__ qhi, bf16* __restrict__ qlo,
    bf16* __restrict__ khi, bf16* __restrict__ klo,
    bf16* __restrict__ vhi, bf16* __restrict__ vlo,
    bf16* __restrict__ wt) {
    const int WW = 56, C = 192;
    int bid = blockIdx.x;

    if (bid < 4704) {
        int idx = bid * 256 + threadIdx.x;
        int p  = idx / 48;
        int c4 = (idx - p * 48) * 4;
        int b  = p / 3136;
        int rem = p - b * 3136;
        int oy = rem / 56;
        int ox = rem - oy * 56;
        const float* xb = x + (size_t)b * 3136 * C;

        float4 sc = *(const float4*)&qscale[c4];
        float4 vr = *(const float4*)&qvar[c4];
        float4 bi = *(const float4*)&qbias[c4];
        float4 mn = *(const float4*)&qmean[c4];
        float aA[4] = {sc.x * rsqrtf(vr.x + EPS_BN), sc.y * rsqrtf(vr.y + EPS_BN),
                       sc.z * rsqrtf(vr.z + EPS_BN), sc.w * rsqrtf(vr.w + EPS_BN)};
        float aB[4] = {bi.x - mn.x * aA[0], bi.y - mn.y * aA[1],
                       bi.z - mn.z * aA[2], bi.w - mn.w * aA[3]};
        float s[4] = {0.f, 0.f, 0.f, 0.f};
#pragma unroll
        for (int ky = 0; ky < 3; ky++) {
            int iy = oy + ky - 1;
            bool yok = (iy >= 0) && (iy < 56);
#pragma unroll
            for (int kx = 0; kx < 3; kx++) {
                int ix = ox + kx - 1;
                if (yok && ix >= 0 && ix < WW) {
                    float4 xv = *(const float4*)&xb[((size_t)iy * WW + ix) * C + c4];
                    float4 wv = *(const float4*)&qdw[(ky * 3 + kx) * C + c4];
                    s[0] += xv.x * wv.x; s[1] += xv.y * wv.y;
                    s[2] += xv.z * wv.z; s[3] += xv.w * wv.w;
                }
            }
        }
        bf16x4 hv, lv;
#pragma unroll
        for (int j = 0; j < 4; j++) {
            float av = s[j] * aA[j] + aB[j];
            bf16 hh = (bf16)av;
            hv[j] = hh;
            lv[j] = (bf16)(av - (float)hh);
        }
        *(bf16x4*)&qhi[(size_t)p * C + c4] = hv;
        *(bf16x4*)&qlo[(size_t)p * C + c4] = lv;
    } else if (bid < 5880) {
        int idx = (bid - 4704) * 256 + threadIdx.x;
        int p  = idx / 48;
        int c4 = (idx - p * 48) * 4;
        int b  = p / 784;
        int rem = p - b * 784;
        int oy = rem / 28;
        int ox = rem - oy * 28;
        const float* xb = x + (size_t)b * 3136 * C;

        float ks[4] = {0.f, 0.f, 0.f, 0.f};
        float vs[4] = {0.f, 0.f, 0.f, 0.f};
#pragma unroll
        for (int ky = 0; ky < 3; ky++) {
            int iy = oy * 2 + ky;
            bool yok = iy < 56;
#pragma unroll
            for (int kx = 0; kx < 3; kx++) {
                int ix = ox * 2 + kx;
                if (yok && ix < WW) {
                    float4 xv = *(const float4*)&xb[((size_t)iy * WW + ix) * C + c4];
                    float4 kw = *(const float4*)&kdw[(ky * 3 + kx) * C + c4];
                    float4 vw = *(const float4*)&vdw[(ky * 3 + kx) * C + c4];
                    ks[0] += xv.x * kw.x; ks[1] += xv.y * kw.y;
                    ks[2] += xv.z * kw.z; ks[3] += xv.w * kw.w;
                    vs[0] += xv.x * vw.x; vs[1] += xv.y * vw.y;
                    vs[2] += xv.z * vw.z; vs[3] += xv.w * vw.w;
                }
            }
        }
        float4 ksc = *(const float4*)&kscale[c4];
        float4 kvr = *(const float4*)&kvar[c4];
        float4 kbi = *(const float4*)&kbias[c4];
        float4 kmn = *(const float4*)&kmean[c4];
        float4 vsc = *(const float4*)&vscale[c4];
        float4 vvr = *(const float4*)&vvar[c4];
        float4 vbi = *(const float4*)&vbias[c4];
        float4 vmn = *(const float4*)&vmean[c4];
        float kA[4] = {ksc.x * rsqrtf(kvr.x + EPS_BN), ksc.y * rsqrtf(kvr.y + EPS_BN),
                       ksc.z * rsqrtf(kvr.z + EPS_BN), ksc.w * rsqrtf(kvr.w + EPS_BN)};
        float kB[4] = {kbi.x - kmn.x * kA[0], kbi.y - kmn.y * kA[1],
                       kbi.z - kmn.z * kA[2], kbi.w - kmn.w * kA[3]};
        float vA[4] = {vsc.x * rsqrtf(vvr.x + EPS_BN), vsc.y * rsqrtf(vvr.y + EPS_BN),
                       vsc.z * rsqrtf(vvr.z + EPS_BN), vsc.w * rsqrtf(vvr.w + EPS_BN)};
        float vB[4] = {vbi.x - vmn.x * vA[0], vbi.y - vmn.y * vA[1],
                       vbi.z - vmn.z * vA[2], vbi.w - vmn.w * vA[3]};
        bf16x4 kh, kl, vh, vl;
#pragma unroll
        for (int j = 0; j < 4; j++) {
            float kf = ks[j] * kA[j] + kB[j];
            float vf = vs[j] * vA[j] + vB[j];
            bf16 h1 = (bf16)kf; kh[j] = h1; kl[j] = (bf16)(kf - (float)h1);
            bf16 h2 = (bf16)vf; vh[j] = h2; vl[j] = (bf16)(vf - (float)h2);
        }
        *(bf16x4*)&khi[(size_t)p * C + c4] = kh;
        *(bf16x4*)&klo[(size_t)p * C + c4] = kl;
        *(bf16x4*)&vhi[(size_t)p * C + c4] = vh;
        *(bf16x4*)&vlo[(size_t)p * C + c4] = vl;
    } else {
        int idx = (bid - 5880) * 256 + threadIdx.x;
        if (idx < 3 * 36864) {
            int mat = idx / 36864, r = idx % 36864;
            int n = r / 192, k = r - n * 192;
            const float* src = (mat == 0) ? qpw : (mat == 1) ? kpw : vpw;
            wt[idx] = (bf16)src[k * 192 + n];
        }
    }
}

// ---------------------------------------------------------------------------
// Kernel 2: all three pointwise GEMMs in one launch. (only change vs R7:
// Q epilogue scale folds log2(e) so attention can use raw exp2.)
// ---------------------------------------------------------------------------
__global__ __launch_bounds__(256) void gemm_all_kernel(
    const bf16* __restrict__ qhi, const bf16* __restrict__ qlo,
    const bf16* __restrict__ khi, const bf16* __restrict__ klo,
    const bf16* __restrict__ vhi, const bf16* __restrict__ vlo,
    const bf16* __restrict__ wt,
    bf16* __restrict__ qbuf, bf16* __restrict__ kbuf, bf16* __restrict__ vtbuf) {
    __shared__ bf16 Ws[192][200];
    int t = threadIdx.x;
    int bid = blockIdx.x;

    int mode, mt;
    const bf16 *Ahi, *Alo, *Wsrc;
    if (bid < 392)      { mode = 0; mt = bid;       Ahi = qhi; Alo = qlo; Wsrc = wt; }
    else if (bid < 490) { mode = 1; mt = bid - 392; Ahi = khi; Alo = klo; Wsrc = wt + 36864; }
    else                { mode = 2; mt = bid - 490; Ahi = vhi; Alo = vlo; Wsrc = wt + 73728; }

#pragma unroll
    for (int it = 0; it < 18; it++) {
        int idx = it * 256 + t;
        int n = idx / 24, ck = idx - n * 24;
        *(uint4*)&Ws[n][ck * 8] = *(const uint4*)&Wsrc[n * 192 + ck * 8];
    }
    __syncthreads();

    int lane = t & 63, wid = t >> 6;
    int l16 = lane & 15, quad = lane >> 4;
    int wrow = wid * 16;
    int m0 = mt * 64;

    f32x4 acc[12];
#pragma unroll
    for (int n = 0; n < 12; n++) acc[n] = f32x4{0.f, 0.f, 0.f, 0.f};

    const bf16* arh = Ahi + (size_t)(m0 + wrow + l16) * 192;
    const bf16* arl = Alo + (size_t)(m0 + wrow + l16) * 192;
#pragma unroll
    for (int kc = 0; kc < 6; kc++) {
        bf16x8 ah = *(const bf16x8*)(arh + kc * 32 + quad * 8);
        bf16x8 al = *(const bf16x8*)(arl + kc * 32 + quad * 8);
#pragma unroll
        for (int n = 0; n < 12; n++) {
            bf16x8 bfr = *(const bf16x8*)&Ws[n * 16 + l16][kc * 32 + quad * 8];
            acc[n] = __builtin_amdgcn_mfma_f32_16x16x32_bf16(al, bfr, acc[n], 0, 0, 0);
            acc[n] = __builtin_amdgcn_mfma_f32_16x16x32_bf16(ah, bfr, acc[n], 0, 0, 0);
        }
    }

    if (mode == 2) {
#pragma unroll
        for (int reg = 0; reg < 4; reg++) {
            int row = m0 + wrow + quad * 4 + reg;
            int b = row / 784;
            int loc = row - b * 784;
#pragma unroll
            for (int n = 0; n < 12; n++) {
                int col = n * 16 + l16;
                int h = col >> 6, d = col & 63;
                vtbuf[(((size_t)b * 3 + h) * 64 + d) * 784 + loc] = (bf16)acc[n][reg];
            }
        }
    } else {
        bf16* outp = (mode == 0) ? qbuf : kbuf;
        // 0.125 * log2(e): logits land in log2 units -> raw v_exp_f32 in attn
        const float s = (mode == 0) ? 0.18033688f : 1.0f;
#pragma unroll
        for (int reg = 0; reg < 4; reg++) {
            size_t row = m0 + wrow + quad * 4 + reg;
#pragma unroll
            for (int n = 0; n < 12; n++)
                outp[row * 192 + n * 16 + l16] = (bf16)(acc[n][reg] * s);
        }
    }
}

// ---------------------------------------------------------------------------
// Kernel 4: flash attention, S^T form, ZERO-staging / ZERO-barrier K-loop.
// Both K and V fragments are contiguous 16-B runs in global memory for the
// transposed formulation, and K/V are L2-resident (200 KB per (b,h), shared
// by 49 blocks) -> read fragments directly from global, no LDS staging, no
// __syncthreads at all (Ps is wave-local). Softmax in exp2 domain (log2e
// pre-folded into q). waves_per_eu(4,4): 128-VGPR budget, ~90 live -> no
// spill (R5 lesson), 4 waves/EU headroom.
// ---------------------------------------------------------------------------
__global__ __launch_bounds__(256)
__attribute__((amdgpu_waves_per_eu(4, 4)))
void attn4_kernel(const bf16* __restrict__ qb,
                  const bf16* __restrict__ kb,
                  const bf16* __restrict__ vtb,
                  float* __restrict__ out) {
    const int LQ = 3136, LK = 784, C = 192;
    int qt = blockIdx.x, h = blockIdx.y, b = blockIdx.z;

    __shared__ bf16 Ps[64][136];    // [q][key-in-chunk], cols 112..127 zeroed

    int t    = threadIdx.x;
    int lane = t & 63;
    int wid  = t >> 6;
    int l16  = lane & 15;
    int quad = lane >> 4;
    int wrow = wid * 16;

    // zero own pad cols (wave-local rows -> no barrier ever needed)
    {
        bf16x4 z = {(bf16)0.f, (bf16)0.f, (bf16)0.f, (bf16)0.f};
        *(bf16x4*)&Ps[wrow + l16][112 + quad * 4] = z;
    }

    // Q fragments (B operand: n = q = l16, k = d) in registers
    bf16x8 qfrag[2];
    {
        const bf16* qrow = qb + ((size_t)b * LQ + qt * 64 + wrow + l16) * C + h * 64;
        qfrag[0] = *(const bf16x8*)(qrow + quad * 8);
        qfrag[1] = *(const bf16x8*)(qrow + 32 + quad * 8);
    }

    const bf16* kbase  = kb + (size_t)b * LK * C + h * 64;
    const bf16* vtbase = vtb + ((size_t)(b * 3 + h)) * 64 * LK;

    float m_run = -INFINITY, l_run = 0.f;
    f32x4 o_acc[4];
#pragma unroll
    for (int dt = 0; dt < 4; dt++) o_acc[dt] = f32x4{0.f, 0.f, 0.f, 0.f};

    for (int c = 0; c < 7; c++) {
        int j0 = c * 112;

        // S^T = K Q^T : A-frags straight from global K (L2-hot, 16B runs)
        f32x4 st[7];
#pragma unroll
        for (int kb7 = 0; kb7 < 7; kb7++) st[kb7] = f32x4{0.f, 0.f, 0.f, 0.f};
#pragma unroll
        for (int kk = 0; kk < 2; kk++) {
#pragma unroll
            for (int kb7 = 0; kb7 < 7; kb7++) {
                bf16x8 afrag = *(const bf16x8*)(kbase + (size_t)(j0 + kb7 * 16 + l16) * C + kk * 32 + quad * 8);
                st[kb7] = __builtin_amdgcn_mfma_f32_16x16x32_bf16(afrag, qfrag[kk], st[kb7], 0, 0, 0);
            }
        }

        // online softmax (base-2) for q = l16; cross-quad shuffle reductions
        float mx = -INFINITY;
#pragma unroll
        for (int kb7 = 0; kb7 < 7; kb7++)
#pragma unroll
            for (int r = 0; r < 4; r++) mx = fmaxf(mx, st[kb7][r]);
        mx = fmaxf(mx, __shfl_xor(mx, 16, 64));
        mx = fmaxf(mx, __shfl_xor(mx, 32, 64));
        float m_new = fmaxf(m_run, mx);
        float alpha = exp2f(m_run - m_new);   // chunk 0: exp2(-inf)=0

        float rs = 0.f;
#pragma unroll
        for (int kb7 = 0; kb7 < 7; kb7++) {
            bf16x4 pv;
#pragma unroll
            for (int r = 0; r < 4; r++) {
                float p = exp2f(st[kb7][r] - m_new);
                rs += p;
                pv[r] = (bf16)p;
            }
            *(bf16x4*)&Ps[wrow + l16][kb7 * 16 + quad * 4] = pv;
        }
        rs += __shfl_xor(rs, 16, 64);
        rs += __shfl_xor(rs, 32, 64);
        l_run = l_run * alpha + rs;
        m_run = m_new;
#pragma unroll
        for (int dt = 0; dt < 4; dt++)
#pragma unroll
            for (int r = 0; r < 4; r++) o_acc[dt][r] *= alpha;

        // O^T += Vt P^T : A-frags straight from global Vt (16B runs).
        // kk=3, quad>=2 addresses the zero-P pad keys -> clamp to key 0
        // (any finite value x P=0 contributes nothing).
#pragma unroll
        for (int kk = 0; kk < 4; kk++) {
            bf16x8 pfrag = *(const bf16x8*)&Ps[wrow + l16][kk * 32 + quad * 8];
            int loc = kk * 32 + quad * 8;
            int koff = (loc < 112) ? (j0 + loc) : 0;
#pragma unroll
            for (int dt = 0; dt < 4; dt++) {
                bf16x8 vfrag = *(const bf16x8*)(vtbase + (size_t)(dt * 16 + l16) * LK + koff);
                o_acc[dt] = __builtin_amdgcn_mfma_f32_16x16x32_bf16(vfrag, pfrag, o_acc[dt], 0, 0, 0);
            }
        }
    }

    // epilogue: lane holds q = l16, d = dt*16 + quad*4 + reg -> float4 stores
    float invl = 1.f / l_run;
    float* ob = out + ((size_t)b * LQ + qt * 64 + wrow + l16) * C + h * 64;
#pragma unroll
    for (int dt = 0; dt < 4; dt++) {
        float4 v4 = {o_acc[dt][0] * invl, o_acc[dt][1] * invl,
                     o_acc[dt][2] * invl, o_acc[dt][3] * invl};
        *(float4*)(ob + dt * 16 + quad * 4) = v4;
    }
}

// ---------------------------------------------------------------------------
extern "C" void kernel_launch(void* const* d_in, const int* in_sizes, int n_in,
                              void* d_out, int out_size, void* d_ws, size_t ws_size,
                              hipStream_t stream) {
    const float* x = (const float*)d_in[0];

    const float* q_dw = (const float*)d_in[1];
    const float* q_scale = (const float*)d_in[2];
    const float* q_bias = (const float*)d_in[3];
    const float* q_mean = (const float*)d_in[4];
    const float* q_var = (const float*)d_in[5];
    const float* q_pw = (const float*)d_in[6];

    const float* k_dw = (const float*)d_in[7];
    const float* k_scale = (const float*)d_in[8];
    const float* k_bias = (const float*)d_in[9];
    const float* k_mean = (const float*)d_in[10];
    const float* k_var = (const float*)d_in[11];
    const float* k_pw = (const float*)d_in[12];

    const float* v_dw = (const float*)d_in[13];
    const float* v_scale = (const float*)d_in[14];
    const float* v_bias = (const float*)d_in[15];
    const float* v_mean = (const float*)d_in[16];
    const float* v_var = (const float*)d_in[17];
    const float* v_pw = (const float*)d_in[18];

    float* out = (float*)d_out;

    // workspace layout (bytes, all 16B aligned)
    char* ws = (char*)d_ws;
    bf16* qhi = (bf16*)(ws);                  // 9,633,792
    bf16* qlo = (bf16*)(ws + 9633792);        // 9,633,792
    bf16* khi = (bf16*)(ws + 19267584);       // 2,408,448
    bf16* klo = (bf16*)(ws + 21676032);       // 2,408,448
    bf16* vhi = (bf16*)(ws + 24084480);       // 2,408,448
    bf16* vlo = (bf16*)(ws + 26492928);       // 2,408,448
    bf16* qbuf = (bf16*)(ws + 28901376);      // 9,633,792
    bf16* kbuf = (bf16*)(ws + 38535168);      // 2,408,448
    bf16* vtbuf = (bf16*)(ws + 40943616);     // 2,408,448
    bf16* wt = (bf16*)(ws + 43352064);        // 221,184

    // stage 1: conv(Q) + conv(K,V) + weight cast, one launch (6312 blocks)
    conv_all_kernel<<<6312, 256, 0, stream>>>(
        x,
        q_dw, q_scale, q_bias, q_mean, q_var,
        k_dw, k_scale, k_bias, k_mean, k_var,
        v_dw, v_scale, v_bias, v_mean, v_var,
        q_pw, k_pw, v_pw,
        qhi, qlo, khi, klo, vhi, vlo, wt);

    // stage 2: all three pointwise GEMMs, one launch (588 blocks)
    gemm_all_kernel<<<588, 256, 0, stream>>>(
        qhi, qlo, khi, klo, vhi, vlo, wt, qbuf, kbuf, vtbuf);

    // stage 3: attention (49 q-tiles, 3 heads, 8 batches)
    attn4_kernel<<<dim3(49, 3, 8), 256, 0, stream>>>(qbuf, kbuf, vtbuf, out);
}

// Round 9
// 260.287 us; speedup vs baseline: 1.0262x; 1.0262x over previous
//
#include <hip/hip_runtime.h>
#include <cmath>

#define EPS_BN 1e-5f

typedef __bf16 bf16;
typedef __bf16 bf16x4 __attribute__((ext_vector_type(4)));
typedef __bf16 bf16x8 __attribute__((ext_vector_type(8)));
typedef float  f32x4  __attribute__((ext_vector_type(4)));

// async global->LDS DMA, 16 B per lane, LDS dest = wave-uniform base + lane*16
__device__ __forceinline__ void dma16(const bf16* g, bf16* l) {
    __builtin_amdgcn_global_load_lds(
        (const __attribute__((address_space(1))) void*)g,
        (__attribute__((address_space(3))) void*)l, 16, 0, 0);
}

// ---------------------------------------------------------------------------
// Kernel 1: all preprocessing elementwise work in one launch. (unchanged)
// ---------------------------------------------------------------------------
__global__ __launch_bounds__(256) void conv_all_kernel(
    const float* __restrict__ x,
    const float* __restrict__ qdw, const float* __restrict__ qscale,
    const float* __restrict__ qbias, const float* __restrict__ qmean,
    const float* __restrict__ qvar,
    const float* __restrict__ kdw, const float* __restrict__ kscale,
    const float* __restrict__ kbias, const float* __restrict__ kmean,
    const float* __restrict__ kvar,
    const float* __restrict__ vdw, const float* __restrict__ vscale,
    const float* __restrict__ vbias, const float* __restrict__ vmean,
    const float* __restrict__ vvar,
    const float* __restrict__ qpw, const float* __restrict__ kpw,
    const float* __restrict__ vpw,
    bf16* __restrict__ qhi, bf16* __restrict__ qlo,
    bf16* __restrict__ khi, bf16* __restrict__ klo,
    bf16* __restrict__ vhi, bf16* __restrict__ vlo,
    bf16* __restrict__ wt) {
    const int WW = 56, C = 192;
    int bid = blockIdx.x;

    if (bid < 4704) {
        int idx = bid * 256 + threadIdx.x;
        int p  = idx / 48;
        int c4 = (idx - p * 48) * 4;
        int b  = p / 3136;
        int rem = p - b * 3136;
        int oy = rem / 56;
        int ox = rem - oy * 56;
        const float* xb = x + (size_t)b * 3136 * C;

        float4 sc = *(const float4*)&qscale[c4];
        float4 vr = *(const float4*)&qvar[c4];
        float4 bi = *(const float4*)&qbias[c4];
        float4 mn = *(const float4*)&qmean[c4];
        float aA[4] = {sc.x * rsqrtf(vr.x + EPS_BN), sc.y * rsqrtf(vr.y + EPS_BN),
                       sc.z * rsqrtf(vr.z + EPS_BN), sc.w * rsqrtf(vr.w + EPS_BN)};
        float aB[4] = {bi.x - mn.x * aA[0], bi.y - mn.y * aA[1],
                       bi.z - mn.z * aA[2], bi.w - mn.w * aA[3]};
        float s[4] = {0.f, 0.f, 0.f, 0.f};
#pragma unroll
        for (int ky = 0; ky < 3; ky++) {
            int iy = oy + ky - 1;
            bool yok = (iy >= 0) && (iy < 56);
#pragma unroll
            for (int kx = 0; kx < 3; kx++) {
                int ix = ox + kx - 1;
                if (yok && ix >= 0 && ix < WW) {
                    float4 xv = *(const float4*)&xb[((size_t)iy * WW + ix) * C + c4];
                    float4 wv = *(const float4*)&qdw[(ky * 3 + kx) * C + c4];
                    s[0] += xv.x * wv.x; s[1] += xv.y * wv.y;
                    s[2] += xv.z * wv.z; s[3] += xv.w * wv.w;
                }
            }
        }
        bf16x4 hv, lv;
#pragma unroll
        for (int j = 0; j < 4; j++) {
            float av = s[j] * aA[j] + aB[j];
            bf16 hh = (bf16)av;
            hv[j] = hh;
            lv[j] = (bf16)(av - (float)hh);
        }
        *(bf16x4*)&qhi[(size_t)p * C + c4] = hv;
        *(bf16x4*)&qlo[(size_t)p * C + c4] = lv;
    } else if (bid < 5880) {
        int idx = (bid - 4704) * 256 + threadIdx.x;
        int p  = idx / 48;
        int c4 = (idx - p * 48) * 4;
        int b  = p / 784;
        int rem = p - b * 784;
        int oy = rem / 28;
        int ox = rem - oy * 28;
        const float* xb = x + (size_t)b * 3136 * C;

        float ks[4] = {0.f, 0.f, 0.f, 0.f};
        float vs[4] = {0.f, 0.f, 0.f, 0.f};
#pragma unroll
        for (int ky = 0; ky < 3; ky++) {
            int iy = oy * 2 + ky;
            bool yok = iy < 56;
#pragma unroll
            for (int kx = 0; kx < 3; kx++) {
                int ix = ox * 2 + kx;
                if (yok && ix < WW) {
                    float4 xv = *(const float4*)&xb[((size_t)iy * WW + ix) * C + c4];
                    float4 kw = *(const float4*)&kdw[(ky * 3 + kx) * C + c4];
                    float4 vw = *(const float4*)&vdw[(ky * 3 + kx) * C + c4];
                    ks[0] += xv.x * kw.x; ks[1] += xv.y * kw.y;
                    ks[2] += xv.z * kw.z; ks[3] += xv.w * kw.w;
                    vs[0] += xv.x * vw.x; vs[1] += xv.y * vw.y;
                    vs[2] += xv.z * vw.z; vs[3] += xv.w * vw.w;
                }
            }
        }
        float4 ksc = *(const float4*)&kscale[c4];
        float4 kvr = *(const float4*)&kvar[c4];
        float4 kbi = *(const float4*)&kbias[c4];
        float4 kmn = *(const float4*)&kmean[c4];
        float4 vsc = *(const float4*)&vscale[c4];
        float4 vvr = *(const float4*)&vvar[c4];
        float4 vbi = *(const float4*)&vbias[c4];
        float4 vmn = *(const float4*)&vmean[c4];
        float kA[4] = {ksc.x * rsqrtf(kvr.x + EPS_BN), ksc.y * rsqrtf(kvr.y + EPS_BN),
                       ksc.z * rsqrtf(kvr.z + EPS_BN), ksc.w * rsqrtf(kvr.w + EPS_BN)};
        float kB[4] = {kbi.x - kmn.x * kA[0], kbi.y - kmn.y * kA[1],
                       kbi.z - kmn.z * kA[2], kbi.w - kmn.w * kA[3]};
        float vA[4] = {vsc.x * rsqrtf(vvr.x + EPS_BN), vsc.y * rsqrtf(vvr.y + EPS_BN),
                       vsc.z * rsqrtf(vvr.z + EPS_BN), vsc.w * rsqrtf(vvr.w + EPS_BN)};
        float vB[4] = {vbi.x - vmn.x * vA[0], vbi.y - vmn.y * vA[1],
                       vbi.z - vmn.z * vA[2], vbi.w - vmn.w * vA[3]};
        bf16x4 kh, kl, vh, vl;
#pragma unroll
        for (int j = 0; j < 4; j++) {
            float kf = ks[j] * kA[j] + kB[j];
            float vf = vs[j] * vA[j] + vB[j];
            bf16 h1 = (bf16)kf; kh[j] = h1; kl[j] = (bf16)(kf - (float)h1);
            bf16 h2 = (bf16)vf; vh[j] = h2; vl[j] = (bf16)(vf - (float)h2);
        }
        *(bf16x4*)&khi[(size_t)p * C + c4] = kh;
        *(bf16x4*)&klo[(size_t)p * C + c4] = kl;
        *(bf16x4*)&vhi[(size_t)p * C + c4] = vh;
        *(bf16x4*)&vlo[(size_t)p * C + c4] = vl;
    } else {
        int idx = (bid - 5880) * 256 + threadIdx.x;
        if (idx < 3 * 36864) {
            int mat = idx / 36864, r = idx % 36864;
            int n = r / 192, k = r - n * 192;
            const float* src = (mat == 0) ? qpw : (mat == 1) ? kpw : vpw;
            wt[idx] = (bf16)src[k * 192 + n];
        }
    }
}

// ---------------------------------------------------------------------------
// Kernel 2: all three pointwise GEMMs in one launch. (unchanged from R8:
// Q epilogue folds 0.125*log2(e) so attention softmax runs in exp2 domain.)
// ---------------------------------------------------------------------------
__global__ __launch_bounds__(256) void gemm_all_kernel(
    const bf16* __restrict__ qhi, const bf16* __restrict__ qlo,
    const bf16* __restrict__ khi, const bf16* __restrict__ klo,
    const bf16* __restrict__ vhi, const bf16* __restrict__ vlo,
    const bf16* __restrict__ wt,
    bf16* __restrict__ qbuf, bf16* __restrict__ kbuf, bf16* __restrict__ vtbuf) {
    __shared__ bf16 Ws[192][200];
    int t = threadIdx.x;
    int bid = blockIdx.x;

    int mode, mt;
    const bf16 *Ahi, *Alo, *Wsrc;
    if (bid < 392)      { mode = 0; mt = bid;       Ahi = qhi; Alo = qlo; Wsrc = wt; }
    else if (bid < 490) { mode = 1; mt = bid - 392; Ahi = khi; Alo = klo; Wsrc = wt + 36864; }
    else                { mode = 2; mt = bid - 490; Ahi = vhi; Alo = vlo; Wsrc = wt + 73728; }

#pragma unroll
    for (int it = 0; it < 18; it++) {
        int idx = it * 256 + t;
        int n = idx / 24, ck = idx - n * 24;
        *(uint4*)&Ws[n][ck * 8] = *(const uint4*)&Wsrc[n * 192 + ck * 8];
    }
    __syncthreads();

    int lane = t & 63, wid = t >> 6;
    int l16 = lane & 15, quad = lane >> 4;
    int wrow = wid * 16;
    int m0 = mt * 64;

    f32x4 acc[12];
#pragma unroll
    for (int n = 0; n < 12; n++) acc[n] = f32x4{0.f, 0.f, 0.f, 0.f};

    const bf16* arh = Ahi + (size_t)(m0 + wrow + l16) * 192;
    const bf16* arl = Alo + (size_t)(m0 + wrow + l16) * 192;
#pragma unroll
    for (int kc = 0; kc < 6; kc++) {
        bf16x8 ah = *(const bf16x8*)(arh + kc * 32 + quad * 8);
        bf16x8 al = *(const bf16x8*)(arl + kc * 32 + quad * 8);
#pragma unroll
        for (int n = 0; n < 12; n++) {
            bf16x8 bfr = *(const bf16x8*)&Ws[n * 16 + l16][kc * 32 + quad * 8];
            acc[n] = __builtin_amdgcn_mfma_f32_16x16x32_bf16(al, bfr, acc[n], 0, 0, 0);
            acc[n] = __builtin_amdgcn_mfma_f32_16x16x32_bf16(ah, bfr, acc[n], 0, 0, 0);
        }
    }

    if (mode == 2) {
#pragma unroll
        for (int reg = 0; reg < 4; reg++) {
            int row = m0 + wrow + quad * 4 + reg;
            int b = row / 784;
            int loc = row - b * 784;
#pragma unroll
            for (int n = 0; n < 12; n++) {
                int col = n * 16 + l16;
                int h = col >> 6, d = col & 63;
                vtbuf[(((size_t)b * 3 + h) * 64 + d) * 784 + loc] = (bf16)acc[n][reg];
            }
        }
    } else {
        bf16* outp = (mode == 0) ? qbuf : kbuf;
        // 0.125 * log2(e): logits in log2 units -> raw v_exp_f32 in attn
        const float s = (mode == 0) ? 0.18033688f : 1.0f;
#pragma unroll
        for (int reg = 0; reg < 4; reg++) {
            size_t row = m0 + wrow + quad * 4 + reg;
#pragma unroll
            for (int n = 0; n < 12; n++)
                outp[row * 192 + n * 16 + l16] = (bf16)(acc[n][reg] * s);
        }
    }
}

// ---------------------------------------------------------------------------
// Kernel 5: flash attention, S^T form, DMA staging (R7-verified), now with
// TWO q-tiles (128 q rows) per block: each K/V chunk DMA is amortized over
// 2x the MFMA work (60 vs 30 MFMAs/wave/chunk) and staging traffic halves.
// exp2-domain softmax (log2e folded into q by gemm_all). Ps is reused across
// tiles (wave-local rows; same-wave LDS ops are ordered -> no extra barrier).
// R8 lesson: direct global MFMA operands are 384B-strided = uncoalesced;
// LDS-DMA staging IS the coalescer. R5 lesson: no VGPR-held prefetch.
// ---------------------------------------------------------------------------
__global__ __launch_bounds__(256)
__attribute__((amdgpu_waves_per_eu(3, 3)))
void attn5_kernel(const bf16* __restrict__ qb,
                  const bf16* __restrict__ kb,
                  const bf16* __restrict__ vtb,
                  float* __restrict__ out) {
    const int LQ = 3136, LK = 784, C = 192;
    int qp = blockIdx.x;              // 0..24 (pair of 64-row q-tiles)
    int h  = blockIdx.y, b = blockIdx.z;
    int ntiles = (qp < 24) ? 2 : 1;   // 3136 = 24*128 + 64

    __shared__ bf16 Ks[8192];        // 112 rows x 72 (flat) + tail guard
    __shared__ bf16 Vts[64][136];    // [d][key], keys 112..127 garbage
    __shared__ bf16 Ps[64][136];     // [q][key], cols 112..127 zeroed once

    int t    = threadIdx.x;
    int lane = t & 63;
    int wid  = t >> 6;
    int l16  = lane & 15;
    int quad = lane >> 4;
    int wrow = wid * 16;

    // zero Ps pad cols once (annihilate Vt pad garbage in PV MFMA)
    if (t < 128) {
        int row = t >> 1, part = t & 1;
        *(uint4*)&Ps[row][112 + part * 8] = make_uint4(0u, 0u, 0u, 0u);
    }

    // Q fragments for both tiles (B operand: n = q = l16, k = d)
    bf16x8 qfrag[2][2];
#pragma unroll
    for (int tl = 0; tl < 2; tl++) {
        int row = qp * 128 + ((tl < ntiles) ? tl : 0) * 64 + wrow + l16;
        const bf16* qrow = qb + ((size_t)b * LQ + row) * C + h * 64;
        qfrag[tl][0] = *(const bf16x8*)(qrow + quad * 8);
        qfrag[tl][1] = *(const bf16x8*)(qrow + 32 + quad * 8);
    }

    const bf16* kbase  = kb + (size_t)b * LK * C + h * 64;
    const bf16* vtbase = vtb + ((size_t)(b * 3 + h)) * 64 * LK;

    float m_run[2] = {-INFINITY, -INFINITY};
    float l_run[2] = {0.f, 0.f};
    f32x4 o_acc[2][4];
#pragma unroll
    for (int tl = 0; tl < 2; tl++)
#pragma unroll
        for (int dt = 0; dt < 4; dt++) o_acc[tl][dt] = f32x4{0.f, 0.f, 0.f, 0.f};

    for (int c = 0; c < 7; c++) {
        int j0 = c * 112;
        __syncthreads();   // prior chunk's LDS readers done (c=0: pad zeros)

        // issue async DMA: 33 stripes round-robined over 4 waves
        for (int s = wid; s < 33; s += 4) {
            if (s < 16) {
                int j = s * 64 + lane;           // chunk idx into Ks (9/row)
                int r = j / 9, cc = j - r * 9;
                const bf16* src = (cc < 8 && r < 112)
                                  ? kbase + (size_t)(j0 + r) * C + cc * 8
                                  : kbase;       // finite garbage into pads
                dma16(src, &Ks[s * 512]);
            } else {
                int s2 = s - 16;
                int j = s2 * 64 + lane;          // chunk idx into Vts (17/row)
                int r = j / 17, cc = j - r * 17;
                const bf16* src = (cc < 14)
                                  ? vtbase + (size_t)r * LK + j0 + cc * 8
                                  : vtbase;      // finite garbage into pads
                dma16(src, (bf16*)Vts + s2 * 512);
            }
        }
        __syncthreads();   // drains vmcnt -> DMA data visible

        for (int tl = 0; tl < ntiles; tl++) {
            // S^T = K Q^T : 7 key-tiles x (K-dim 64 = 2 steps)
            f32x4 st[7];
#pragma unroll
            for (int kb7 = 0; kb7 < 7; kb7++) st[kb7] = f32x4{0.f, 0.f, 0.f, 0.f};
#pragma unroll
            for (int kk = 0; kk < 2; kk++) {
#pragma unroll
                for (int kb7 = 0; kb7 < 7; kb7++) {
                    bf16x8 afrag = *(const bf16x8*)&Ks[(kb7 * 16 + l16) * 72 + kk * 32 + quad * 8];
                    st[kb7] = __builtin_amdgcn_mfma_f32_16x16x32_bf16(afrag, qfrag[tl][kk], st[kb7], 0, 0, 0);
                }
            }

            // online softmax (base-2) for q = l16; cross-quad shuffles
            float mx = -INFINITY;
#pragma unroll
            for (int kb7 = 0; kb7 < 7; kb7++)
#pragma unroll
                for (int r = 0; r < 4; r++) mx = fmaxf(mx, st[kb7][r]);
            mx = fmaxf(mx, __shfl_xor(mx, 16, 64));
            mx = fmaxf(mx, __shfl_xor(mx, 32, 64));
            float m_new = fmaxf(m_run[tl], mx);
            float alpha = exp2f(m_run[tl] - m_new);   // chunk 0: exp2(-inf)=0

            float rs = 0.f;
#pragma unroll
            for (int kb7 = 0; kb7 < 7; kb7++) {
                bf16x4 pv;
#pragma unroll
                for (int r = 0; r < 4; r++) {
                    float p = exp2f(st[kb7][r] - m_new);
                    rs += p;
                    pv[r] = (bf16)p;
                }
                *(bf16x4*)&Ps[wrow + l16][kb7 * 16 + quad * 4] = pv;
            }
            rs += __shfl_xor(rs, 16, 64);
            rs += __shfl_xor(rs, 32, 64);
            l_run[tl] = l_run[tl] * alpha + rs;
            m_run[tl] = m_new;
#pragma unroll
            for (int dt = 0; dt < 4; dt++)
#pragma unroll
                for (int r = 0; r < 4; r++) o_acc[tl][dt][r] *= alpha;

            // O^T += Vt P^T : keys 128 (16 zero-P-padded) = 4 steps
#pragma unroll
            for (int kk = 0; kk < 4; kk++) {
                bf16x8 pfrag = *(const bf16x8*)&Ps[wrow + l16][kk * 32 + quad * 8];
#pragma unroll
                for (int dt = 0; dt < 4; dt++) {
                    bf16x8 vfrag = *(const bf16x8*)&Vts[dt * 16 + l16][kk * 32 + quad * 8];
                    o_acc[tl][dt] = __builtin_amdgcn_mfma_f32_16x16x32_bf16(vfrag, pfrag, o_acc[tl][dt], 0, 0, 0);
                }
            }
        }
    }

    // epilogue: lane holds q = l16, d = dt*16 + quad*4 + reg -> float4 stores
    for (int tl = 0; tl < ntiles; tl++) {
        float invl = 1.f / l_run[tl];
        float* ob = out + ((size_t)b * LQ + qp * 128 + tl * 64 + wrow + l16) * C + h * 64;
#pragma unroll
        for (int dt = 0; dt < 4; dt++) {
            float4 v4 = {o_acc[tl][dt][0] * invl, o_acc[tl][dt][1] * invl,
                         o_acc[tl][dt][2] * invl, o_acc[tl][dt][3] * invl};
            *(float4*)(ob + dt * 16 + quad * 4) = v4;
        }
    }
}

// ---------------------------------------------------------------------------
extern "C" void kernel_launch(void* const* d_in, const int* in_sizes, int n_in,
                              void* d_out, int out_size, void* d_ws, size_t ws_size,
                              hipStream_t stream) {
    const float* x = (const float*)d_in[0];

    const float* q_dw = (const float*)d_in[1];
    const float* q_scale = (const float*)d_in[2];
    const float* q_bias = (const float*)d_in[3];
    const float* q_mean = (const float*)d_in[4];
    const float* q_var = (const float*)d_in[5];
    const float* q_pw = (const float*)d_in[6];

    const float* k_dw = (const float*)d_in[7];
    const float* k_scale = (const float*)d_in[8];
    const float* k_bias = (const float*)d_in[9];
    const float* k_mean = (const float*)d_in[10];
    const float* k_var = (const float*)d_in[11];
    const float* k_pw = (const float*)d_in[12];

    const float* v_dw = (const float*)d_in[13];
    const float* v_scale = (const float*)d_in[14];
    const float* v_bias = (const float*)d_in[15];
    const float* v_mean = (const float*)d_in[16];
    const float* v_var = (const float*)d_in[17];
    const float* v_pw = (const float*)d_in[18];

    float* out = (float*)d_out;

    // workspace layout (bytes, all 16B aligned)
    char* ws = (char*)d_ws;
    bf16* qhi = (bf16*)(ws);                  // 9,633,792
    bf16* qlo = (bf16*)(ws + 9633792);        // 9,633,792
    bf16* khi = (bf16*)(ws + 19267584);       // 2,408,448
    bf16* klo = (bf16*)(ws + 21676032);       // 2,408,448
    bf16* vhi = (bf16*)(ws + 24084480);       // 2,408,448
    bf16* vlo = (bf16*)(ws + 26492928);       // 2,408,448
    bf16* qbuf = (bf16*)(ws + 28901376);      // 9,633,792
    bf16* kbuf = (bf16*)(ws + 38535168);      // 2,408,448
    bf16* vtbuf = (bf16*)(ws + 40943616);     // 2,408,448
    bf16* wt = (bf16*)(ws + 43352064);        // 221,184

    // stage 1: conv(Q) + conv(K,V) + weight cast, one launch (6312 blocks)
    conv_all_kernel<<<6312, 256, 0, stream>>>(
        x,
        q_dw, q_scale, q_bias, q_mean, q_var,
        k_dw, k_scale, k_bias, k_mean, k_var,
        v_dw, v_scale, v_bias, v_mean, v_var,
        q_pw, k_pw, v_pw,
        qhi, qlo, khi, klo, vhi, vlo, wt);

    // stage 2: all three pointwise GEMMs, one launch (588 blocks)
    gemm_all_kernel<<<588, 256, 0, stream>>>(
        qhi, qlo, khi, klo, vhi, vlo, wt, qbuf, kbuf, vtbuf);

    // stage 3: attention (25 q-pairs, 3 heads, 8 batches)
    attn5_kernel<<<dim3(25, 3, 8), 256, 0, stream>>>(qbuf, kbuf, vtbuf, out);
}

// Round 10
// 191.936 us; speedup vs baseline: 1.3917x; 1.3561x over previous
//
#include <hip/hip_runtime.h>
#include <cmath>

#define EPS_BN 1e-5f

typedef __bf16 bf16;
typedef __bf16 bf16x4 __attribute__((ext_vector_type(4)));
typedef __bf16 bf16x8 __attribute__((ext_vector_type(8)));
typedef float  f32x4  __attribute__((ext_vector_type(4)));

// async global->LDS DMA, 16 B per lane, LDS dest = wave-uniform base + lane*16
__device__ __forceinline__ void dma16(const bf16* g, bf16* l) {
    __builtin_amdgcn_global_load_lds(
        (const __attribute__((address_space(1))) void*)g,
        (__attribute__((address_space(3))) void*)l, 16, 0, 0);
}

// ---------------------------------------------------------------------------
// Kernel 1: all preprocessing elementwise work in one launch. (unchanged)
// ---------------------------------------------------------------------------
__global__ __launch_bounds__(256) void conv_all_kernel(
    const float* __restrict__ x,
    const float* __restrict__ qdw, const float* __restrict__ qscale,
    const float* __restrict__ qbias, const float* __restrict__ qmean,
    const float* __restrict__ qvar,
    const float* __restrict__ kdw, const float* __restrict__ kscale,
    const float* __restrict__ kbias, const float* __restrict__ kmean,
    const float* __restrict__ kvar,
    const float* __restrict__ vdw, const float* __restrict__ vscale,
    const float* __restrict__ vbias, const float* __restrict__ vmean,
    const float* __restrict__ vvar,
    const float* __restrict__ qpw, const float* __restrict__ kpw,
    const float* __restrict__ vpw,
    bf16* __restrict__ qhi, bf16* __restrict__ qlo,
    bf16* __restrict__ khi, bf16* __restrict__ klo,
    bf16* __restrict__ vhi, bf16* __restrict__ vlo,
    bf16* __restrict__ wt) {
    const int WW = 56, C = 192;
    int bid = blockIdx.x;

    if (bid < 4704) {
        int idx = bid * 256 + threadIdx.x;
        int p  = idx / 48;
        int c4 = (idx - p * 48) * 4;
        int b  = p / 3136;
        int rem = p - b * 3136;
        int oy = rem / 56;
        int ox = rem - oy * 56;
        const float* xb = x + (size_t)b * 3136 * C;

        float4 sc = *(const float4*)&qscale[c4];
        float4 vr = *(const float4*)&qvar[c4];
        float4 bi = *(const float4*)&qbias[c4];
        float4 mn = *(const float4*)&qmean[c4];
        float aA[4] = {sc.x * rsqrtf(vr.x + EPS_BN), sc.y * rsqrtf(vr.y + EPS_BN),
                       sc.z * rsqrtf(vr.z + EPS_BN), sc.w * rsqrtf(vr.w + EPS_BN)};
        float aB[4] = {bi.x - mn.x * aA[0], bi.y - mn.y * aA[1],
                       bi.z - mn.z * aA[2], bi.w - mn.w * aA[3]};
        float s[4] = {0.f, 0.f, 0.f, 0.f};
#pragma unroll
        for (int ky = 0; ky < 3; ky++) {
            int iy = oy + ky - 1;
            bool yok = (iy >= 0) && (iy < 56);
#pragma unroll
            for (int kx = 0; kx < 3; kx++) {
                int ix = ox + kx - 1;
                if (yok && ix >= 0 && ix < WW) {
                    float4 xv = *(const float4*)&xb[((size_t)iy * WW + ix) * C + c4];
                    float4 wv = *(const float4*)&qdw[(ky * 3 + kx) * C + c4];
                    s[0] += xv.x * wv.x; s[1] += xv.y * wv.y;
                    s[2] += xv.z * wv.z; s[3] += xv.w * wv.w;
                }
            }
        }
        bf16x4 hv, lv;
#pragma unroll
        for (int j = 0; j < 4; j++) {
            float av = s[j] * aA[j] + aB[j];
            bf16 hh = (bf16)av;
            hv[j] = hh;
            lv[j] = (bf16)(av - (float)hh);
        }
        *(bf16x4*)&qhi[(size_t)p * C + c4] = hv;
        *(bf16x4*)&qlo[(size_t)p * C + c4] = lv;
    } else if (bid < 5880) {
        int idx = (bid - 4704) * 256 + threadIdx.x;
        int p  = idx / 48;
        int c4 = (idx - p * 48) * 4;
        int b  = p / 784;
        int rem = p - b * 784;
        int oy = rem / 28;
        int ox = rem - oy * 28;
        const float* xb = x + (size_t)b * 3136 * C;

        float ks[4] = {0.f, 0.f, 0.f, 0.f};
        float vs[4] = {0.f, 0.f, 0.f, 0.f};
#pragma unroll
        for (int ky = 0; ky < 3; ky++) {
            int iy = oy * 2 + ky;
            bool yok = iy < 56;
#pragma unroll
            for (int kx = 0; kx < 3; kx++) {
                int ix = ox * 2 + kx;
                if (yok && ix < WW) {
                    float4 xv = *(const float4*)&xb[((size_t)iy * WW + ix) * C + c4];
                    float4 kw = *(const float4*)&kdw[(ky * 3 + kx) * C + c4];
                    float4 vw = *(const float4*)&vdw[(ky * 3 + kx) * C + c4];
                    ks[0] += xv.x * kw.x; ks[1] += xv.y * kw.y;
                    ks[2] += xv.z * kw.z; ks[3] += xv.w * kw.w;
                    vs[0] += xv.x * vw.x; vs[1] += xv.y * vw.y;
                    vs[2] += xv.z * vw.z; vs[3] += xv.w * vw.w;
                }
            }
        }
        float4 ksc = *(const float4*)&kscale[c4];
        float4 kvr = *(const float4*)&kvar[c4];
        float4 kbi = *(const float4*)&kbias[c4];
        float4 kmn = *(const float4*)&kmean[c4];
        float4 vsc = *(const float4*)&vscale[c4];
        float4 vvr = *(const float4*)&vvar[c4];
        float4 vbi = *(const float4*)&vbias[c4];
        float4 vmn = *(const float4*)&vmean[c4];
        float kA[4] = {ksc.x * rsqrtf(kvr.x + EPS_BN), ksc.y * rsqrtf(kvr.y + EPS_BN),
                       ksc.z * rsqrtf(kvr.z + EPS_BN), ksc.w * rsqrtf(kvr.w + EPS_BN)};
        float kB[4] = {kbi.x - kmn.x * kA[0], kbi.y - kmn.y * kA[1],
                       kbi.z - kmn.z * kA[2], kbi.w - kmn.w * kA[3]};
        float vA[4] = {vsc.x * rsqrtf(vvr.x + EPS_BN), vsc.y * rsqrtf(vvr.y + EPS_BN),
                       vsc.z * rsqrtf(vvr.z + EPS_BN), vsc.w * rsqrtf(vvr.w + EPS_BN)};
        float vB[4] = {vbi.x - vmn.x * vA[0], vbi.y - vmn.y * vA[1],
                       vbi.z - vmn.z * vA[2], vbi.w - vmn.w * vA[3]};
        bf16x4 kh, kl, vh, vl;
#pragma unroll
        for (int j = 0; j < 4; j++) {
            float kf = ks[j] * kA[j] + kB[j];
            float vf = vs[j] * vA[j] + vB[j];
            bf16 h1 = (bf16)kf; kh[j] = h1; kl[j] = (bf16)(kf - (float)h1);
            bf16 h2 = (bf16)vf; vh[j] = h2; vl[j] = (bf16)(vf - (float)h2);
        }
        *(bf16x4*)&khi[(size_t)p * C + c4] = kh;
        *(bf16x4*)&klo[(size_t)p * C + c4] = kl;
        *(bf16x4*)&vhi[(size_t)p * C + c4] = vh;
        *(bf16x4*)&vlo[(size_t)p * C + c4] = vl;
    } else {
        int idx = (bid - 5880) * 256 + threadIdx.x;
        if (idx < 3 * 36864) {
            int mat = idx / 36864, r = idx % 36864;
            int n = r / 192, k = r - n * 192;
            const float* src = (mat == 0) ? qpw : (mat == 1) ? kpw : vpw;
            wt[idx] = (bf16)src[k * 192 + n];
        }
    }
}

// ---------------------------------------------------------------------------
// Kernel 2: all three pointwise GEMMs in one launch. (unchanged:
// Q epilogue folds 0.125*log2(e) so attention softmax runs in exp2 domain.)
// ---------------------------------------------------------------------------
__global__ __launch_bounds__(256) void gemm_all_kernel(
    const bf16* __restrict__ qhi, const bf16* __restrict__ qlo,
    const bf16* __restrict__ khi, const bf16* __restrict__ klo,
    const bf16* __restrict__ vhi, const bf16* __restrict__ vlo,
    const bf16* __restrict__ wt,
    bf16* __restrict__ qbuf, bf16* __restrict__ kbuf, bf16* __restrict__ vtbuf) {
    __shared__ bf16 Ws[192][200];
    int t = threadIdx.x;
    int bid = blockIdx.x;

    int mode, mt;
    const bf16 *Ahi, *Alo, *Wsrc;
    if (bid < 392)      { mode = 0; mt = bid;       Ahi = qhi; Alo = qlo; Wsrc = wt; }
    else if (bid < 490) { mode = 1; mt = bid - 392; Ahi = khi; Alo = klo; Wsrc = wt + 36864; }
    else                { mode = 2; mt = bid - 490; Ahi = vhi; Alo = vlo; Wsrc = wt + 73728; }

#pragma unroll
    for (int it = 0; it < 18; it++) {
        int idx = it * 256 + t;
        int n = idx / 24, ck = idx - n * 24;
        *(uint4*)&Ws[n][ck * 8] = *(const uint4*)&Wsrc[n * 192 + ck * 8];
    }
    __syncthreads();

    int lane = t & 63, wid = t >> 6;
    int l16 = lane & 15, quad = lane >> 4;
    int wrow = wid * 16;
    int m0 = mt * 64;

    f32x4 acc[12];
#pragma unroll
    for (int n = 0; n < 12; n++) acc[n] = f32x4{0.f, 0.f, 0.f, 0.f};

    const bf16* arh = Ahi + (size_t)(m0 + wrow + l16) * 192;
    const bf16* arl = Alo + (size_t)(m0 + wrow + l16) * 192;
#pragma unroll
    for (int kc = 0; kc < 6; kc++) {
        bf16x8 ah = *(const bf16x8*)(arh + kc * 32 + quad * 8);
        bf16x8 al = *(const bf16x8*)(arl + kc * 32 + quad * 8);
#pragma unroll
        for (int n = 0; n < 12; n++) {
            bf16x8 bfr = *(const bf16x8*)&Ws[n * 16 + l16][kc * 32 + quad * 8];
            acc[n] = __builtin_amdgcn_mfma_f32_16x16x32_bf16(al, bfr, acc[n], 0, 0, 0);
            acc[n] = __builtin_amdgcn_mfma_f32_16x16x32_bf16(ah, bfr, acc[n], 0, 0, 0);
        }
    }

    if (mode == 2) {
#pragma unroll
        for (int reg = 0; reg < 4; reg++) {
            int row = m0 + wrow + quad * 4 + reg;
            int b = row / 784;
            int loc = row - b * 784;
#pragma unroll
            for (int n = 0; n < 12; n++) {
                int col = n * 16 + l16;
                int h = col >> 6, d = col & 63;
                vtbuf[(((size_t)b * 3 + h) * 64 + d) * 784 + loc] = (bf16)acc[n][reg];
            }
        }
    } else {
        bf16* outp = (mode == 0) ? qbuf : kbuf;
        // 0.125 * log2(e): logits in log2 units -> raw v_exp_f32 in attn
        const float s = (mode == 0) ? 0.18033688f : 1.0f;
#pragma unroll
        for (int reg = 0; reg < 4; reg++) {
            size_t row = m0 + wrow + quad * 4 + reg;
#pragma unroll
            for (int n = 0; n < 12; n++)
                outp[row * 192 + n * 16 + l16] = (bf16)(acc[n][reg] * s);
        }
    }
}

// ---------------------------------------------------------------------------
// Kernel 6: attn5 with the dynamic-indexing bug fixed. The tile loop is now
// a compile-time #pragma unroll 2 (constant bounds) so qfrag/o_acc/m_run/
// l_run are statically indexed registers — R9's runtime `ntiles` bound made
// them dynamically-indexed arrays => lowered to scratch => 190 MB/dispatch
// spill traffic. Tail block (qp==24) computes tile 1 as a clamped duplicate
// and skips its store (1/600 blocks wasted — negligible).
// ---------------------------------------------------------------------------
__global__ __launch_bounds__(256)
__attribute__((amdgpu_waves_per_eu(3, 3)))
void attn6_kernel(const bf16* __restrict__ qb,
                  const bf16* __restrict__ kb,
                  const bf16* __restrict__ vtb,
                  float* __restrict__ out) {
    const int LQ = 3136, LK = 784, C = 192;
    int qp = blockIdx.x;              // 0..24 (pair of 64-row q-tiles)
    int h  = blockIdx.y, b = blockIdx.z;
    bool tile1_valid = (qp < 24);     // 3136 = 24*128 + 64

    __shared__ bf16 Ks[8192];        // 112 rows x 72 (flat) + tail guard
    __shared__ bf16 Vts[64][136];    // [d][key], keys 112..127 garbage
    __shared__ bf16 Ps[64][136];     // [q][key], cols 112..127 zeroed once

    int t    = threadIdx.x;
    int lane = t & 63;
    int wid  = t >> 6;
    int l16  = lane & 15;
    int quad = lane >> 4;
    int wrow = wid * 16;

    // zero Ps pad cols once (annihilate Vt pad garbage in PV MFMA)
    if (t < 128) {
        int row = t >> 1, part = t & 1;
        *(uint4*)&Ps[row][112 + part * 8] = make_uint4(0u, 0u, 0u, 0u);
    }

    // Q fragments for both tiles (B operand: n = q = l16, k = d)
    bf16x8 qfrag[2][2];
#pragma unroll
    for (int tl = 0; tl < 2; tl++) {
        int tloff = (tl == 1 && tile1_valid) ? 64 : 0;   // tail: clamp to tile 0
        int row = qp * 128 + tloff + wrow + l16;
        const bf16* qrow = qb + ((size_t)b * LQ + row) * C + h * 64;
        qfrag[tl][0] = *(const bf16x8*)(qrow + quad * 8);
        qfrag[tl][1] = *(const bf16x8*)(qrow + 32 + quad * 8);
    }

    const bf16* kbase  = kb + (size_t)b * LK * C + h * 64;
    const bf16* vtbase = vtb + ((size_t)(b * 3 + h)) * 64 * LK;

    float m_run[2] = {-INFINITY, -INFINITY};
    float l_run[2] = {0.f, 0.f};
    f32x4 o_acc[2][4];
#pragma unroll
    for (int tl = 0; tl < 2; tl++)
#pragma unroll
        for (int dt = 0; dt < 4; dt++) o_acc[tl][dt] = f32x4{0.f, 0.f, 0.f, 0.f};

    for (int c = 0; c < 7; c++) {
        int j0 = c * 112;
        __syncthreads();   // prior chunk's LDS readers done (c=0: pad zeros)

        // issue async DMA: 33 stripes round-robined over 4 waves
        for (int s = wid; s < 33; s += 4) {
            if (s < 16) {
                int j = s * 64 + lane;           // chunk idx into Ks (9/row)
                int r = j / 9, cc = j - r * 9;
                const bf16* src = (cc < 8 && r < 112)
                                  ? kbase + (size_t)(j0 + r) * C + cc * 8
                                  : kbase;       // finite garbage into pads
                dma16(src, &Ks[s * 512]);
            } else {
                int s2 = s - 16;
                int j = s2 * 64 + lane;          // chunk idx into Vts (17/row)
                int r = j / 17, cc = j - r * 17;
                const bf16* src = (cc < 14)
                                  ? vtbase + (size_t)r * LK + j0 + cc * 8
                                  : vtbase;      // finite garbage into pads
                dma16(src, (bf16*)Vts + s2 * 512);
            }
        }
        __syncthreads();   // drains vmcnt -> DMA data visible

#pragma unroll
        for (int tl = 0; tl < 2; tl++) {
            // S^T = K Q^T : 7 key-tiles x (K-dim 64 = 2 steps)
            f32x4 st[7];
#pragma unroll
            for (int kb7 = 0; kb7 < 7; kb7++) st[kb7] = f32x4{0.f, 0.f, 0.f, 0.f};
#pragma unroll
            for (int kk = 0; kk < 2; kk++) {
#pragma unroll
                for (int kb7 = 0; kb7 < 7; kb7++) {
                    bf16x8 afrag = *(const bf16x8*)&Ks[(kb7 * 16 + l16) * 72 + kk * 32 + quad * 8];
                    st[kb7] = __builtin_amdgcn_mfma_f32_16x16x32_bf16(afrag, qfrag[tl][kk], st[kb7], 0, 0, 0);
                }
            }

            // online softmax (base-2) for q = l16; cross-quad shuffles
            float mx = -INFINITY;
#pragma unroll
            for (int kb7 = 0; kb7 < 7; kb7++)
#pragma unroll
                for (int r = 0; r < 4; r++) mx = fmaxf(mx, st[kb7][r]);
            mx = fmaxf(mx, __shfl_xor(mx, 16, 64));
            mx = fmaxf(mx, __shfl_xor(mx, 32, 64));
            float m_new = fmaxf(m_run[tl], mx);
            float alpha = exp2f(m_run[tl] - m_new);   // chunk 0: exp2(-inf)=0

            float rs = 0.f;
#pragma unroll
            for (int kb7 = 0; kb7 < 7; kb7++) {
                bf16x4 pv;
#pragma unroll
                for (int r = 0; r < 4; r++) {
                    float p = exp2f(st[kb7][r] - m_new);
                    rs += p;
                    pv[r] = (bf16)p;
                }
                *(bf16x4*)&Ps[wrow + l16][kb7 * 16 + quad * 4] = pv;
            }
            rs += __shfl_xor(rs, 16, 64);
            rs += __shfl_xor(rs, 32, 64);
            l_run[tl] = l_run[tl] * alpha + rs;
            m_run[tl] = m_new;
#pragma unroll
            for (int dt = 0; dt < 4; dt++)
#pragma unroll
                for (int r = 0; r < 4; r++) o_acc[tl][dt][r] *= alpha;

            // O^T += Vt P^T : keys 128 (16 zero-P-padded) = 4 steps
#pragma unroll
            for (int kk = 0; kk < 4; kk++) {
                bf16x8 pfrag = *(const bf16x8*)&Ps[wrow + l16][kk * 32 + quad * 8];
#pragma unroll
                for (int dt = 0; dt < 4; dt++) {
                    bf16x8 vfrag = *(const bf16x8*)&Vts[dt * 16 + l16][kk * 32 + quad * 8];
                    o_acc[tl][dt] = __builtin_amdgcn_mfma_f32_16x16x32_bf16(vfrag, pfrag, o_acc[tl][dt], 0, 0, 0);
                }
            }
        }
    }

    // epilogue: lane holds q = l16, d = dt*16 + quad*4 + reg -> float4 stores
#pragma unroll
    for (int tl = 0; tl < 2; tl++) {
        if (tl == 1 && !tile1_valid) break;
        float invl = 1.f / l_run[tl];
        float* ob = out + ((size_t)b * LQ + qp * 128 + tl * 64 + wrow + l16) * C + h * 64;
#pragma unroll
        for (int dt = 0; dt < 4; dt++) {
            float4 v4 = {o_acc[tl][dt][0] * invl, o_acc[tl][dt][1] * invl,
                         o_acc[tl][dt][2] * invl, o_acc[tl][dt][3] * invl};
            *(float4*)(ob + dt * 16 + quad * 4) = v4;
        }
    }
}

// ---------------------------------------------------------------------------
extern "C" void kernel_launch(void* const* d_in, const int* in_sizes, int n_in,
                              void* d_out, int out_size, void* d_ws, size_t ws_size,
                              hipStream_t stream) {
    const float* x = (const float*)d_in[0];

    const float* q_dw = (const float*)d_in[1];
    const float* q_scale = (const float*)d_in[2];
    const float* q_bias = (const float*)d_in[3];
    const float* q_mean = (const float*)d_in[4];
    const float* q_var = (const float*)d_in[5];
    const float* q_pw = (const float*)d_in[6];

    const float* k_dw = (const float*)d_in[7];
    const float* k_scale = (const float*)d_in[8];
    const float* k_bias = (const float*)d_in[9];
    const float* k_mean = (const float*)d_in[10];
    const float* k_var = (const float*)d_in[11];
    const float* k_pw = (const float*)d_in[12];

    const float* v_dw = (const float*)d_in[13];
    const float* v_scale = (const float*)d_in[14];
    const float* v_bias = (const float*)d_in[15];
    const float* v_mean = (const float*)d_in[16];
    const float* v_var = (const float*)d_in[17];
    const float* v_pw = (const float*)d_in[18];

    float* out = (float*)d_out;

    // workspace layout (bytes, all 16B aligned)
    char* ws = (char*)d_ws;
    bf16* qhi = (bf16*)(ws);                  // 9,633,792
    bf16* qlo = (bf16*)(ws + 9633792);        // 9,633,792
    bf16* khi = (bf16*)(ws + 19267584);       // 2,408,448
    bf16* klo = (bf16*)(ws + 21676032);       // 2,408,448
    bf16* vhi = (bf16*)(ws + 24084480);       // 2,408,448
    bf16* vlo = (bf16*)(ws + 26492928);       // 2,408,448
    bf16* qbuf = (bf16*)(ws + 28901376);      // 9,633,792
    bf16* kbuf = (bf16*)(ws + 38535168);      // 2,408,448
    bf16* vtbuf = (bf16*)(ws + 40943616);     // 2,408,448
    bf16* wt = (bf16*)(ws + 43352064);        // 221,184

    // stage 1: conv(Q) + conv(K,V) + weight cast, one launch (6312 blocks)
    conv_all_kernel<<<6312, 256, 0, stream>>>(
        x,
        q_dw, q_scale, q_bias, q_mean, q_var,
        k_dw, k_scale, k_bias, k_mean, k_var,
        v_dw, v_scale, v_bias, v_mean, v_var,
        q_pw, k_pw, v_pw,
        qhi, qlo, khi, klo, vhi, vlo, wt);

    // stage 2: all three pointwise GEMMs, one launch (588 blocks)
    gemm_all_kernel<<<588, 256, 0, stream>>>(
        qhi, qlo, khi, klo, vhi, vlo, wt, qbuf, kbuf, vtbuf);

    // stage 3: attention (25 q-pairs, 3 heads, 8 batches)
    attn6_kernel<<<dim3(25, 3, 8), 256, 0, stream>>>(qbuf, kbuf, vtbuf, out);
}